// Round 8
// baseline (277.826 us; speedup 1.0000x reference)
//
#include <hip/hip_runtime.h>
#include <cstdint>
#include <cstddef>

#define B_ROWS 16384
#define D_DIM  1024
#define F_REAL 1034          // real hidden/feature dim
#define NBLK2  96            // padded N = 1536 = 96 * 16 (3 passes x 8 waves x 64)
#define KT_N   33            // 33 K-tiles of 32 (1024 h + 32 tail)
#define EPSN   1e-12f

#define LDS_RF_OFF   65536   // u16 units: panel = 64*1024 u16 = 131072 B
#define LDS_TOTAL    137472  // 131072 (panel) + 256 (rf) + 6144 (comb 8x192 f32)

typedef __bf16 bf16x8 __attribute__((ext_vector_type(8)));
typedef float  f32x4  __attribute__((ext_vector_type(4)));
typedef unsigned short u16;
typedef unsigned int   u32;

__device__ __forceinline__ u16 f2bf(float f) {
    __bf16 b = (__bf16)f;
    return __builtin_bit_cast(u16, b);
}

// -------------------------------------------------------------------------
// prep (unchanged from R7): reads ONLY vp,vh (128 MB), bytes-bound ~53us.
// Writes 10 scalar features per row into Ascal[16384][32]; slot 7
// (r_final) left 0, patched by gemm.
// -------------------------------------------------------------------------
__global__ __launch_bounds__(256)
void prep_kernel(const float* __restrict__ vp,
                 const float* __restrict__ vh, const float* __restrict__ nd,
                 const float* __restrict__ nsp, u16* __restrict__ Ascal)
{
    const int tid  = threadIdx.x;
    const int lane = tid & 63;
    const int wg   = blockIdx.x * 4 + (tid >> 6);   // 0..4095
    const int r0   = wg * 4;

    const float4* ndp = (const float4*)nd;
    float4 n[4];
    #pragma unroll
    for (int c = 0; c < 4; ++c) n[c] = ndp[lane + c * 64];
    const float ns = nsp[0];

    float s_nn = 0.f;
    #pragma unroll
    for (int c = 0; c < 4; ++c)
        s_nn += n[c].x*n[c].x + n[c].y*n[c].y + n[c].z*n[c].z + n[c].w*n[c].w;
    #pragma unroll
    for (int m = 32; m >= 1; m >>= 1) s_nn += __shfl_xor(s_nn, m, 64);
    const float nnc = fmaxf(sqrtf(s_nn), EPSN);

    float4 P[2][4], Q[2][4];

#define LOADR(st, r)                                                          \
    do {                                                                      \
        const float4* vpp = (const float4*)(vp + (size_t)(r) * D_DIM);        \
        const float4* vhp = (const float4*)(vh + (size_t)(r) * D_DIM);        \
        _Pragma("unroll")                                                     \
        for (int c = 0; c < 4; ++c) P[st][c] = vpp[lane + c * 64];            \
        _Pragma("unroll")                                                     \
        for (int c = 0; c < 4; ++c) Q[st][c] = vhp[lane + c * 64];            \
    } while (0)

    LOADR(0, r0);
    #pragma unroll
    for (int i = 0; i < 4; ++i) {
        const int st = i & 1;
        if (i + 1 < 4) LOADR(((i + 1) & 1), r0 + i + 1);
        __builtin_amdgcn_sched_barrier(0);

        float s_pp = 0.f, s_hh = 0.f, s_pv = 0.f;
        float s_dd = 0.f, s_pn = 0.f, s_hn = 0.f;
        #pragma unroll
        for (int c = 0; c < 4; ++c) {
            float4 p = P[st][c], q = Q[st][c], nn = n[c];
            s_pp += p.x*p.x + p.y*p.y + p.z*p.z + p.w*p.w;
            s_hh += q.x*q.x + q.y*q.y + q.z*q.z + q.w*q.w;
            s_pv += p.x*q.x + p.y*q.y + p.z*q.z + p.w*q.w;
            float dx = q.x-p.x, dy = q.y-p.y, dz = q.z-p.z, dw = q.w-p.w;
            s_dd += dx*dx + dy*dy + dz*dz + dw*dw;
            s_pn += p.x*nn.x + p.y*nn.y + p.z*nn.z + p.w*nn.w;
            s_hn += q.x*nn.x + q.y*nn.y + q.z*nn.z + q.w*nn.w;
        }

        #pragma unroll
        for (int m = 32; m >= 1; m >>= 1) {
            s_pp += __shfl_xor(s_pp, m, 64);
            s_hh += __shfl_xor(s_hh, m, 64);
            s_pv += __shfl_xor(s_pv, m, 64);
            s_dd += __shfl_xor(s_dd, m, 64);
            s_pn += __shfl_xor(s_pn, m, 64);
            s_hn += __shfl_xor(s_hn, m, 64);
        }

        if (lane == 0) {
            float np_ = sqrtf(s_pp), nh_ = sqrtf(s_hh);
            float npc = fmaxf(np_, EPSN), nhc = fmaxf(nh_, EPSN);
            float align = s_pv / (npc * nhc);
            u16 fo[32];
            fo[0] = f2bf(align);
            fo[1] = f2bf(-align);
            fo[2] = f2bf(0.5f * (1.0f + align));      // K_O = 1
            fo[3] = f2bf(0.5f * (1.0f - align));
            fo[4] = f2bf(sqrtf(s_dd));
            fo[5] = f2bf(np_);
            fo[6] = f2bf(nh_);
            fo[7] = 0;                                // r_final patched by gemm
            fo[8] = f2bf(ns * s_pn / (npc * nnc));
            fo[9] = f2bf(ns * s_hn / (nhc * nnc));
            #pragma unroll
            for (int k = 10; k < 32; ++k) fo[k] = 0;
            u16* arow = Ascal + (size_t)(r0 + i) * 32;
            #pragma unroll
            for (int k = 0; k < 4; ++k)
                *(uint4*)(arow + k * 8) = *(uint4*)(fo + k * 8);
        }
    }
#undef LOADR
}

// -------------------------------------------------------------------------
// convw (R8: 96 n-blocks): w1 -> frag-contiguous bf16 Bm2[kt][nblk][lane][8]
// 202752 chunks = 792 blocks x 256.
// -------------------------------------------------------------------------
__global__ __launch_bounds__(256)
void convw_kernel(const float* __restrict__ w1, u16* __restrict__ Bm2)
{
    const int o = blockIdx.x * 256 + threadIdx.x;   // chunk id, < 202752
    const int col  = o & 15;
    int t = o >> 4;
    const int quad = t & 3;
    t >>= 2;
    const int nblk = t % NBLK2;
    const int kt   = t / NBLK2;
    const int n = nblk * 16 + col;
    const int k = kt * 32 + quad * 8;

    u16 v[8];
    if (n < F_REAL && k + 7 < F_REAL) {
        const float* src = w1 + (size_t)n * F_REAL + k;
        #pragma unroll
        for (int e = 0; e < 8; e += 2) {
            float2 f = *(const float2*)(src + e);
            v[e]   = f2bf(f.x);
            v[e+1] = f2bf(f.y);
        }
    } else {
        #pragma unroll
        for (int e = 0; e < 8; ++e) {
            float f = (n < F_REAL && k + e < F_REAL)
                        ? w1[(size_t)n * F_REAL + k + e] : 0.0f;
            v[e] = f2bf(f);
        }
    }
    *(uint4*)(Bm2 + (size_t)o * 8) = *(uint4*)v;
}

// -------------------------------------------------------------------------
// GEMM R8: panel-resident, 512 THREADS (8 waves = 2 waves/SIMD).
// R7 diagnosis: Occupancy 10.3% == 1 wave/SIMD -> pure latency exposure
// (MfmaUtil 21 / VALUBusy 26 / HBM 7). Same panel (1 block/CU, 128KB),
// 2x the waves: N padded to 1536, 3 passes of 512 cols (8 waves x 64n).
// A2 ssq restructured 16-lanes/row (was 4/row @ 256B stride = 4-way bank
// conflict, the 2.88M counter); now stride-8B across lanes = 2-way (free).
// K-loop unchanged: no barriers, depth-2 register pipeline, B straight
// from L2 frag-contiguous. Epilogue: 8-wave LDS combine, plain stores.
// -------------------------------------------------------------------------
__global__ __launch_bounds__(512, 2)
void gemm_kernel(const float* __restrict__ h, const u16* __restrict__ Ascal,
                 const u16* __restrict__ Bm2, const float* __restrict__ b1,
                 const float* __restrict__ w2, const float* __restrict__ b2,
                 float* __restrict__ out)
{
    extern __shared__ u16 smem[];
    u16*   panel = smem;                          // [64][1024] swizzled
    float* rf    = (float*)(smem + LDS_RF_OFF);   // 64 floats
    float* comb  = rf + 64;                       // 1536 floats

    const int tid  = threadIdx.x;
    const int lane = tid & 63;
    const int wv   = tid >> 6;      // 0..7 = n-slice of 64
    const int col  = lane & 15;
    const int quad = lane >> 4;
    const int bm   = blockIdx.x;

    // ---- Phase A: h (f32, global, read once) -> bf16 LDS panel ----
    {
        const float* hblk = h + (size_t)bm * 64 * D_DIM;
        const int halfsel = tid & 1;
        const int chunkid = (tid >> 1) & 127;
        const int rpair   = tid >> 8;             // 0..1
        #pragma unroll
        for (int jb = 0; jb < 4; ++jb) {
            float4 v[8];
            #pragma unroll
            for (int u = 0; u < 8; ++u) {
                const int j = jb*16 + u*2 + rpair;
                v[u] = *(const float4*)(hblk + (size_t)j*D_DIM + (tid & 255)*4);
            }
            #pragma unroll
            for (int u = 0; u < 8; ++u) {
                const int j = jb*16 + u*2 + rpair;
                ushort4 o;
                o.x = f2bf(v[u].x); o.y = f2bf(v[u].y);
                o.z = f2bf(v[u].z); o.w = f2bf(v[u].w);
                *(ushort4*)(panel + j*1024 + ((chunkid ^ (j&7))*8) + halfsel*4) = o;
            }
        }
    }
    __syncthreads();

    // ---- Phase A2: per-row ssq -> rf.  16 lanes/row, 8B lane stride ----
    {
        const int s = tid & 15;
        #pragma unroll
        for (int sweep = 0; sweep < 2; ++sweep) {
            const int r = sweep*32 + (tid >> 4);
            float ssq = 0.f;
            #pragma unroll
            for (int c = 0; c < 8; ++c) {
                uint4 tch = *(const uint4*)(panel + r*1024 + (s + c*16)*8);
                u32 wd[4] = {tch.x, tch.y, tch.z, tch.w};
                #pragma unroll
                for (int e = 0; e < 4; ++e) {
                    float lo = __uint_as_float(wd[e] << 16);
                    float hi = __uint_as_float(wd[e] & 0xFFFF0000u);
                    ssq += lo*lo + hi*hi;
                }
            }
            ssq += __shfl_xor(ssq, 1, 64);
            ssq += __shfl_xor(ssq, 2, 64);
            ssq += __shfl_xor(ssq, 4, 64);
            ssq += __shfl_xor(ssq, 8, 64);
            if (s == 0) rf[r] = sqrtf(ssq);
        }
    }
    __syncthreads();

    u16 rfb[4];
    #pragma unroll
    for (int i = 0; i < 4; ++i) rfb[i] = f2bf(rf[i*16 + col]);

    const int xmask = col & 7;
    int arow[4];
    #pragma unroll
    for (int i = 0; i < 4; ++i) arow[i] = (i*16 + col) * 1024;

    float cacc[3][4][4];
    #pragma unroll
    for (int cls = 0; cls < 3; ++cls)
        #pragma unroll
        for (int mi = 0; mi < 4; ++mi)
            #pragma unroll
            for (int r = 0; r < 4; ++r) cacc[cls][mi][r] = 0.f;

    for (int bnp = 0; bnp < 3; ++bnp) {
        const int nblk0 = bnp*32 + wv*4;          // 8 waves x 4 nblk = 512 cols
        float bias[4], w20[4], w21[4], w22[4];
        #pragma unroll
        for (int ni = 0; ni < 4; ++ni) {
            const int n = (nblk0 + ni)*16 + col;
            const bool vok = n < F_REAL;
            bias[ni] = vok ? b1[n] : 0.f;
            w20[ni]  = vok ? w2[n] : 0.f;
            w21[ni]  = vok ? w2[F_REAL + n] : 0.f;
            w22[ni]  = vok ? w2[2*F_REAL + n] : 0.f;
        }
        f32x4 acc[4][4];
        #pragma unroll
        for (int i = 0; i < 4; ++i)
            #pragma unroll
            for (int j = 0; j < 4; ++j)
                acc[i][j] = (f32x4){0.f, 0.f, 0.f, 0.f};

        uint4 avA[4], bvA[4], avB[4], bvB[4], avC[4], bvC[4];

#define LOADF(AV, BV, kt, TAIL)                                               \
    do {                                                                      \
        if (TAIL) {                                                           \
            _Pragma("unroll")                                                 \
            for (int i = 0; i < 4; ++i)                                       \
                AV[i] = *(const uint4*)(Ascal +                               \
                         (size_t)(bm*64 + i*16 + col)*32 + quad*8);           \
        } else {                                                              \
            _Pragma("unroll")                                                 \
            for (int i = 0; i < 4; ++i)                                       \
                AV[i] = *(const uint4*)(panel + arow[i] +                     \
                         ((((kt)*4 + quad) ^ xmask) * 8));                    \
        }                                                                     \
        _Pragma("unroll")                                                     \
        for (int j = 0; j < 4; ++j)                                           \
            BV[j] = *(const uint4*)(Bm2 +                                     \
                     ((size_t)((kt)*NBLK2 + nblk0 + j)*64 + lane)*8);         \
    } while (0)

#define COMPUTE(AV, BV, TAIL)                                                 \
    do {                                                                      \
        bf16x8 a[4], b[4];                                                    \
        _Pragma("unroll")                                                     \
        for (int i = 0; i < 4; ++i) {                                         \
            a[i] = __builtin_bit_cast(bf16x8, AV[i]);                         \
            if (TAIL) { if (quad == 0)                                        \
                a[i][7] = __builtin_bit_cast(__bf16, rfb[i]); }               \
        }                                                                     \
        _Pragma("unroll")                                                     \
        for (int j = 0; j < 4; ++j)                                           \
            b[j] = __builtin_bit_cast(bf16x8, BV[j]);                         \
        _Pragma("unroll")                                                     \
        for (int i = 0; i < 4; ++i)                                           \
            _Pragma("unroll")                                                 \
            for (int j = 0; j < 4; ++j)                                       \
                acc[i][j] = __builtin_amdgcn_mfma_f32_16x16x32_bf16(          \
                                a[i], b[j], acc[i][j], 0, 0, 0);              \
    } while (0)

        // depth-2 register pipeline over 33 K-tiles; no barriers needed
        LOADF(avA, bvA, 0, 0);
        LOADF(avB, bvB, 1, 0);
        for (int it = 0; it < 10; ++it) {
            const int k0 = it * 3;
            LOADF(avC, bvC, k0+2, 0);  COMPUTE(avA, bvA, 0);
            LOADF(avA, bvA, k0+3, 0);  COMPUTE(avB, bvB, 0);
            LOADF(avB, bvB, k0+4, 0);  COMPUTE(avC, bvC, 0);
        }
        LOADF(avC, bvC, 32, 1);  COMPUTE(avA, bvA, 0);   // kt 30
        COMPUTE(avB, bvB, 0);                            // kt 31
        COMPUTE(avC, bvC, 1);                            // kt 32 (tail)

        #pragma unroll
        for (int mi = 0; mi < 4; ++mi)
            #pragma unroll
            for (int ni = 0; ni < 4; ++ni)
                #pragma unroll
                for (int r = 0; r < 4; ++r) {
                    float hd = fmaxf(acc[mi][ni][r] + bias[ni], 0.f);
                    cacc[0][mi][r] += hd * w20[ni];
                    cacc[1][mi][r] += hd * w21[ni];
                    cacc[2][mi][r] += hd * w22[ni];
                }
#undef LOADF
#undef COMPUTE
    }

    // lane-reduce over the 16 cols of each group
    #pragma unroll
    for (int cls = 0; cls < 3; ++cls)
        #pragma unroll
        for (int mi = 0; mi < 4; ++mi)
            #pragma unroll
            for (int r = 0; r < 4; ++r) {
                float v = cacc[cls][mi][r];
                v += __shfl_xor(v, 8, 64);
                v += __shfl_xor(v, 4, 64);
                v += __shfl_xor(v, 2, 64);
                v += __shfl_xor(v, 1, 64);
                cacc[cls][mi][r] = v;
            }

    if (col == 0) {
        #pragma unroll
        for (int cls = 0; cls < 3; ++cls)
            #pragma unroll
            for (int mi = 0; mi < 4; ++mi)
                #pragma unroll
                for (int r = 0; r < 4; ++r)
                    comb[wv*192 + (mi*16 + quad*4 + r)*3 + cls] = cacc[cls][mi][r];
    }
    __syncthreads();
    if (tid < 192) {
        float s = b2[tid % 3];
        #pragma unroll
        for (int w = 0; w < 8; ++w) s += comb[w*192 + tid];
        out[(size_t)bm * 192 + tid] = s;
    }
}

extern "C" void kernel_launch(void* const* d_in, const int* in_sizes, int n_in,
                              void* d_out, int out_size, void* d_ws, size_t ws_size,
                              hipStream_t stream)
{
    const float* h  = (const float*)d_in[0];
    const float* vp = (const float*)d_in[1];
    const float* vh = (const float*)d_in[2];
    const float* nd = (const float*)d_in[3];
    const float* ns = (const float*)d_in[4];
    const float* w1 = (const float*)d_in[5];
    const float* b1 = (const float*)d_in[6];
    const float* w2 = (const float*)d_in[7];
    const float* b2 = (const float*)d_in[8];
    float* out = (float*)d_out;

    u16* Ascal = (u16*)d_ws;                          // [16384][32] bf16
    u16* Bm2   = Ascal + (size_t)B_ROWS * 32;         // [33][96][64][8] bf16

    static bool attr_done = false;
    if (!attr_done) {
        (void)hipFuncSetAttribute((const void*)gemm_kernel,
                                  hipFuncAttributeMaxDynamicSharedMemorySize,
                                  LDS_TOTAL);
        attr_done = true;
    }

    prep_kernel<<<1024, 256, 0, stream>>>(vp, vh, nd, ns, Ascal);
    convw_kernel<<<792, 256, 0, stream>>>(w1, Bm2);
    gemm_kernel<<<256, 512, LDS_TOTAL, stream>>>(h, Ascal, Bm2, b1, w2, b2, out);
}